// Round 13
// baseline (408.020 us; speedup 1.0000x reference)
//
#include <hip/hip_runtime.h>

// 2-layer GCN, R13: agg kernels restructured so one gather instruction serves
// multiple edges (agg1: 2 rows/load via half-wave uint2 lanes; agg2: 4 rows/load
// via quarter-wave). Halves/quarters VMEM instr count and cuts per-edge VALU
// ~30% (R12: agg1 114us @ VALUBusy 44%, neither pipe saturated).
// CSR build (R12 partition, no global atomics) and GEMMs unchanged.

#define N_NODES 100000
#define NBLK  512   // partition blocks
#define NBUCK 391   // ceil(100000/256) buckets of 256 dst nodes

typedef __attribute__((ext_vector_type(8))) short short8;
typedef __attribute__((ext_vector_type(4))) float f32x4;

// ---------- bf16 helpers (RN-even) ----------
__device__ __forceinline__ unsigned short f2bf(float f) {
    union { float f; unsigned u; } c; c.f = f;
    unsigned r = (c.u + 0x7fffu + ((c.u >> 16) & 1u)) >> 16;
    return (unsigned short)r;
}
__device__ __forceinline__ float2 bfpair(unsigned u) {
    union { float f; unsigned u; } a, b;
    a.u = u << 16; b.u = u & 0xffff0000u;
    return make_float2(a.f, b.f);
}
__device__ __forceinline__ unsigned packbf(float a, float b) {
    return (unsigned)f2bf(a) | ((unsigned)f2bf(b) << 16);
}

// ---------- edge dtype detection (one wave) ----------
__global__ void detect64_k(const unsigned long long* __restrict__ ei, int* __restrict__ flag) {
    unsigned long long v = ei[threadIdx.x & 63];
    unsigned long long bad = __ballot(v >= (1ULL << 32));
    if (threadIdx.x == 0) *flag = (bad == 0ULL) ? 1 : 0;
}

__device__ __forceinline__ int edge_at(const void* ei, int is64, long long idx) {
    if (is64) return (int)((const long long*)ei)[idx];
    return ((const int*)ei)[idx];
}

// ---------- pass 1: per-block 391-bucket LDS histogram ----------
__global__ __launch_bounds__(256) void count1_k(const void* __restrict__ ei,
                                                const int* __restrict__ flag,
                                                int* __restrict__ bhist, int E) {
    __shared__ int lh[NBUCK];
    int t = threadIdx.x;
    for (int i = t; i < NBUCK; i += 256) lh[i] = 0;
    __syncthreads();
    int is64 = *flag;
    int C = (E + NBLK - 1) / NBLK;
    int lo = blockIdx.x * C;
    int hi = lo + C; if (hi > E) hi = E;
    for (int e = lo + t; e < hi; e += 256) {
        int d = edge_at(ei, is64, (long long)E + e);
        if ((unsigned)d < (unsigned)N_NODES) atomicAdd(&lh[d >> 8], 1);
    }
    __syncthreads();
    for (int i = t; i < NBUCK; i += 256) bhist[(size_t)i * NBLK + blockIdx.x] = lh[i];
}

// ---------- generic exclusive scan, 1024 elems/block ----------
__global__ void scan1_k(const int* __restrict__ cnt, int* __restrict__ partial,
                        int* __restrict__ bsum, int n) {
    __shared__ int sm[256];
    int t = threadIdx.x;
    int base = blockIdx.x * 1024 + t * 4;
    int v[4]; int loc = 0;
#pragma unroll
    for (int j = 0; j < 4; ++j) { v[j] = (base + j < n) ? cnt[base + j] : 0; loc += v[j]; }
    sm[t] = loc; __syncthreads();
    for (int off = 1; off < 256; off <<= 1) {
        int x = (t >= off) ? sm[t - off] : 0;
        __syncthreads();
        sm[t] += x;
        __syncthreads();
    }
    int incl = sm[t];
    int run = incl - loc;
    if (t == 255) bsum[blockIdx.x] = incl;
#pragma unroll
    for (int j = 0; j < 4; ++j) {
        if (base + j < n) partial[base + j] = run;
        run += v[j];
    }
}

__global__ void scan2_k(int* __restrict__ bsum, int nb) {
    __shared__ int sm[256];
    int t = threadIdx.x;
    int v = (t < nb) ? bsum[t] : 0;
    sm[t] = v; __syncthreads();
    for (int off = 1; off < 256; off <<= 1) {
        int x = (t >= off) ? sm[t - off] : 0;
        __syncthreads();
        sm[t] += x;
        __syncthreads();
    }
    if (t < nb) bsum[t] = sm[t] - v;
}

__global__ void scanadd_k(const int* __restrict__ bsum, int* __restrict__ arr,
                          const int* __restrict__ raw, int* __restrict__ tot, int n) {
    int base = blockIdx.x * 1024 + threadIdx.x * 4;
    int add = bsum[blockIdx.x];
#pragma unroll
    for (int j = 0; j < 4; ++j) {
        int i = base + j;
        if (i < n) {
            int v = arr[i] + add;
            arr[i] = v;
            if (i == n - 1) *tot = v + raw[i];
        }
    }
}

__global__ void scan3_k(const int* __restrict__ bsum, const int* __restrict__ cnt,
                        int* __restrict__ row_ptr, float* __restrict__ dinv, int n) {
    int base = blockIdx.x * 1024 + threadIdx.x * 4;
    int add = bsum[blockIdx.x];
#pragma unroll
    for (int j = 0; j < 4; ++j) {
        int i = base + j;
        if (i < n) {
            row_ptr[i] += add;
            dinv[i] = rsqrtf((float)(cnt[i] + 1));  // +1 self-loop
        }
    }
}

// ---------- pass 2: deterministic staging write (src | dlocal<<17) ----------
__global__ __launch_bounds__(256) void write1_k(const void* __restrict__ ei,
                                                const int* __restrict__ flag,
                                                const int* __restrict__ bbase,
                                                unsigned* __restrict__ pairs, int E) {
    __shared__ int lofs[NBUCK];
    int t = threadIdx.x;
    for (int i = t; i < NBUCK; i += 256) lofs[i] = bbase[(size_t)i * NBLK + blockIdx.x];
    __syncthreads();
    int is64 = *flag;
    int C = (E + NBLK - 1) / NBLK;
    int lo = blockIdx.x * C;
    int hi = lo + C; if (hi > E) hi = E;
    for (int e = lo + t; e < hi; e += 256) {
        int s = edge_at(ei, is64, e);
        int d = edge_at(ei, is64, (long long)E + e);
        if ((unsigned)d >= (unsigned)N_NODES) continue;
        if ((unsigned)s >= (unsigned)N_NODES) s = 0;
        int b = d >> 8;
        int p = atomicAdd(&lofs[b], 1);
        pairs[p] = (unsigned)s | ((unsigned)(d & 255) << 17);
    }
}

// ---------- degrees from staged pairs ----------
__global__ __launch_bounds__(256) void degree_k(const unsigned* __restrict__ pairs,
                                                const int* __restrict__ bbase,
                                                const int* __restrict__ tot,
                                                int* __restrict__ cnt, int Nn) {
    __shared__ int lh[256];
    int b = blockIdx.x;
    int t = threadIdx.x;
    lh[t] = 0;
    __syncthreads();
    int lo = bbase[(size_t)b * NBLK];
    int hi = (b == NBUCK - 1) ? *tot : bbase[((size_t)b + 1) * NBLK];
    for (int i = lo + t; i < hi; i += 256) {
        unsigned p = __builtin_nontemporal_load(pairs + i);
        atomicAdd(&lh[p >> 17], 1);
    }
    __syncthreads();
    int n0 = b << 8;
    if (n0 + t < Nn) cnt[n0 + t] = lh[t];
}

// ---------- pass 3: block-private scatter ----------
__global__ __launch_bounds__(256) void fill3_k(const unsigned* __restrict__ pairs,
                                               const int* __restrict__ bbase,
                                               const int* __restrict__ tot,
                                               const int* __restrict__ row_ptr,
                                               int* __restrict__ colv, int Nn) {
    __shared__ int cur[256];
    int b = blockIdx.x;
    int t = threadIdx.x;
    int n0 = b << 8;
    int nn = Nn - n0; if (nn > 256) nn = 256;
    if (t < nn) cur[t] = row_ptr[n0 + t];
    __syncthreads();
    int lo = bbase[(size_t)b * NBLK];
    int hi = (b == NBUCK - 1) ? *tot : bbase[((size_t)b + 1) * NBLK];
    for (int i = lo + t; i < hi; i += 256) {
        unsigned p = __builtin_nontemporal_load(pairs + i);
        int dl = (int)(p >> 17);
        int slot = atomicAdd(&cur[dl], 1);
        colv[slot] = (int)(p & 0x1FFFFu);
    }
}

// ---------- weight prep: W^T in bf16 ----------
__global__ void prep_w_k(const float* __restrict__ W1, const float* __restrict__ W2,
                         unsigned short* __restrict__ w1bf, unsigned short* __restrict__ w2bf) {
    int i = blockIdx.x * 256 + threadIdx.x;
    if (i < 128 * 128) { int k = i >> 7, f = i & 127; w1bf[f * 128 + k] = f2bf(W1[i]); }
    if (i < 128 * 64)  { int k = i >> 6, f = i & 63;  w2bf[f * 128 + k] = f2bf(W2[i]); }
}

// ---------- GEMM1 (MFMA): h1[n][128] bf16 node-major = x @ W1 ----------
__global__ __launch_bounds__(256) void gemm1_k(const float* __restrict__ x,
                                               const unsigned short* __restrict__ w1bf,
                                               unsigned* __restrict__ h1, int Nn) {
    __shared__ __align__(16) unsigned short sA[128][136];
    __shared__ __align__(16) unsigned short sB[64][136];
    int tid = threadIdx.x;
    int n0g = blockIdx.x * 64;
    {
        const uint4* src = (const uint4*)w1bf;
#pragma unroll
        for (int l = 0; l < 8; ++l) {
            int idx = tid + l * 256;
            int f = idx >> 4, kq = idx & 15;
            *(uint4*)&sA[f][kq * 8] = src[idx];
        }
    }
    {
        int n = tid >> 2, kq = tid & 3;
        int gn = n0g + n; if (gn >= Nn) gn = Nn - 1;
        const float4* xr = (const float4*)(x + (size_t)gn * 128 + kq * 32);
        unsigned short* dst = &sB[n][kq * 32];
#pragma unroll
        for (int i = 0; i < 8; ++i) {
            float4 v = xr[i];
            dst[i * 4 + 0] = f2bf(v.x); dst[i * 4 + 1] = f2bf(v.y);
            dst[i * 4 + 2] = f2bf(v.z); dst[i * 4 + 3] = f2bf(v.w);
        }
    }
    __syncthreads();
    int wave = tid >> 6, lane = tid & 63;
    int quad = lane >> 4, l16 = lane & 15;
    f32x4 z = {0.f, 0.f, 0.f, 0.f};
    f32x4 acc[8];
#pragma unroll
    for (int t = 0; t < 8; ++t) acc[t] = z;
#pragma unroll
    for (int kk = 0; kk < 4; ++kk) {
        int kb = kk * 32 + quad * 8;
        short8 a = *(const short8*)&sB[wave * 16 + l16][kb];
#pragma unroll
        for (int ft = 0; ft < 8; ++ft) {
            short8 b = *(const short8*)&sA[ft * 16 + l16][kb];
            acc[ft] = __builtin_amdgcn_mfma_f32_16x16x32_bf16(a, b, acc[ft], 0, 0, 0);
        }
    }
    __syncthreads();
    unsigned short (*sC)[136] = sA;
#pragma unroll
    for (int ft = 0; ft < 8; ++ft)
#pragma unroll
        for (int r = 0; r < 4; ++r)
            sC[wave * 16 + quad * 4 + r][ft * 16 + l16] = f2bf(acc[ft][r]);
    __syncthreads();
#pragma unroll
    for (int l = 0; l < 4; ++l) {
        int idx = tid + l * 256;
        int row = idx >> 4, q = idx & 15;
        int gn = n0g + row;
        if (gn < Nn)
            *(uint4*)&h1[(size_t)gn * 64 + q * 4] = *(uint4*)&sC[row][q * 8];
    }
}

// ---------- GEMM2 (MFMA): h2[n][64] bf16 node-major = hr @ W2 ----------
__global__ __launch_bounds__(256) void gemm2_k(const unsigned* __restrict__ hr,
                                               const unsigned short* __restrict__ w2bf,
                                               unsigned* __restrict__ h2, int Nn) {
    __shared__ __align__(16) unsigned short sA[64][136];
    __shared__ __align__(16) unsigned short sB[64][136];
    int tid = threadIdx.x;
    int n0g = blockIdx.x * 64;
    {
        const uint4* src = (const uint4*)w2bf;
#pragma unroll
        for (int l = 0; l < 4; ++l) {
            int idx = tid + l * 256;
            int f = idx >> 4, kq = idx & 15;
            *(uint4*)&sA[f][kq * 8] = src[idx];
        }
    }
    {
        const uint4* src = (const uint4*)hr;
#pragma unroll
        for (int l = 0; l < 4; ++l) {
            int idx = tid + l * 256;
            int row = idx >> 4, q = idx & 15;
            int gn = n0g + row; if (gn >= Nn) gn = Nn - 1;
            *(uint4*)&sB[row][q * 8] = src[(size_t)gn * 16 + q];
        }
    }
    __syncthreads();
    int wave = tid >> 6, lane = tid & 63;
    int quad = lane >> 4, l16 = lane & 15;
    f32x4 z = {0.f, 0.f, 0.f, 0.f};
    f32x4 acc[4];
#pragma unroll
    for (int t = 0; t < 4; ++t) acc[t] = z;
#pragma unroll
    for (int kk = 0; kk < 4; ++kk) {
        int kb = kk * 32 + quad * 8;
        short8 a = *(const short8*)&sB[wave * 16 + l16][kb];
#pragma unroll
        for (int ft = 0; ft < 4; ++ft) {
            short8 b = *(const short8*)&sA[ft * 16 + l16][kb];
            acc[ft] = __builtin_amdgcn_mfma_f32_16x16x32_bf16(a, b, acc[ft], 0, 0, 0);
        }
    }
    __syncthreads();
    unsigned short (*sC)[136] = sA;
#pragma unroll
    for (int ft = 0; ft < 4; ++ft)
#pragma unroll
        for (int r = 0; r < 4; ++r)
            sC[wave * 16 + quad * 4 + r][ft * 16 + l16] = f2bf(acc[ft][r]);
    __syncthreads();
#pragma unroll
    for (int l = 0; l < 2; ++l) {
        int idx = tid + l * 256;
        int row = idx >> 3, q = idx & 7;
        int gn = n0g + row;
        if (gn < Nn)
            *(uint4*)&h2[(size_t)gn * 32 + q * 4] = *(uint4*)&sC[row][q * 8];
    }
}

// ---------- agg1: half-wave uint2 lanes -> 2 rows per gather instruction ----------
__global__ __launch_bounds__(256) void agg1_k(const unsigned* __restrict__ h,
                                              const int* __restrict__ row_ptr,
                                              const int* __restrict__ cnt,
                                              const int* __restrict__ colv,
                                              const float* __restrict__ dinv,
                                              const float* __restrict__ bias,
                                              unsigned* __restrict__ out, int Nn, int E) {
    int node = blockIdx.x * 4 + (threadIdx.x >> 6);
    if (node >= Nn) return;
    int lane = threadIdx.x & 63;
    int p = lane >> 5;   // half: which edge of a pair
    int f = lane & 31;   // feat-quad: feats 4f..4f+3 (uint2)
    float di = dinv[node];
    int start = row_ptr[node];
    int deg = cnt[node];

    float a0, a1, a2, a3;
    {
        uint2 hv = *(const uint2*)(h + ((size_t)node << 6) + 2 * f);
        float2 xa = bfpair(hv.x), xb = bfpair(hv.y);
        float w0 = (p == 0) ? di * di : 0.f;
        a0 = w0 * xa.x; a1 = w0 * xa.y; a2 = w0 * xb.x; a3 = w0 * xb.y;
    }
    for (int base = 0; base < deg; base += 64) {
        int idx = base + lane;
        int ci = start + idx; if (ci >= E) ci = E - 1;
        int sl = colv[ci];
        float wl = (idx < deg) ? dinv[sl] : 0.f;
        int m = deg - base; if (m > 64) m = 64;
        int j = 0;
        for (; j + 8 <= m; j += 8) {   // 8 edges = 4 paired loads in flight
            int q0 = j + p, q1 = j + 2 + p, q2 = j + 4 + p, q3 = j + 6 + p;
            int s0 = __shfl(sl, q0), s1 = __shfl(sl, q1);
            int s2 = __shfl(sl, q2), s3 = __shfl(sl, q3);
            float e0 = di * __shfl(wl, q0), e1 = di * __shfl(wl, q1);
            float e2 = di * __shfl(wl, q2), e3 = di * __shfl(wl, q3);
            uint2 u0 = *(const uint2*)(h + ((size_t)s0 << 6) + 2 * f);
            uint2 u1 = *(const uint2*)(h + ((size_t)s1 << 6) + 2 * f);
            uint2 u2 = *(const uint2*)(h + ((size_t)s2 << 6) + 2 * f);
            uint2 u3 = *(const uint2*)(h + ((size_t)s3 << 6) + 2 * f);
            { float2 xa = bfpair(u0.x), xb = bfpair(u0.y);
              a0 = fmaf(e0, xa.x, a0); a1 = fmaf(e0, xa.y, a1);
              a2 = fmaf(e0, xb.x, a2); a3 = fmaf(e0, xb.y, a3); }
            { float2 xa = bfpair(u1.x), xb = bfpair(u1.y);
              a0 = fmaf(e1, xa.x, a0); a1 = fmaf(e1, xa.y, a1);
              a2 = fmaf(e1, xb.x, a2); a3 = fmaf(e1, xb.y, a3); }
            { float2 xa = bfpair(u2.x), xb = bfpair(u2.y);
              a0 = fmaf(e2, xa.x, a0); a1 = fmaf(e2, xa.y, a1);
              a2 = fmaf(e2, xb.x, a2); a3 = fmaf(e2, xb.y, a3); }
            { float2 xa = bfpair(u3.x), xb = bfpair(u3.y);
              a0 = fmaf(e3, xa.x, a0); a1 = fmaf(e3, xa.y, a1);
              a2 = fmaf(e3, xb.x, a2); a3 = fmaf(e3, xb.y, a3); }
        }
        for (; j < m; j += 2) {   // q = j+p <= 63 always (j <= 62)
            int q = j + p;
            int s = __shfl(sl, q);
            float e = di * __shfl(wl, q);
            uint2 u = *(const uint2*)(h + ((size_t)s << 6) + 2 * f);
            float2 xa = bfpair(u.x), xb = bfpair(u.y);
            a0 = fmaf(e, xa.x, a0); a1 = fmaf(e, xa.y, a1);
            a2 = fmaf(e, xb.x, a2); a3 = fmaf(e, xb.y, a3);
        }
    }
    a0 += __shfl_xor(a0, 32, 64); a1 += __shfl_xor(a1, 32, 64);
    a2 += __shfl_xor(a2, 32, 64); a3 += __shfl_xor(a3, 32, 64);
    if (p == 0) {
        float4 bv = *(const float4*)(bias + 4 * f);
        float r0 = fmaxf(a0 + bv.x, 0.f), r1 = fmaxf(a1 + bv.y, 0.f);
        float r2 = fmaxf(a2 + bv.z, 0.f), r3 = fmaxf(a3 + bv.w, 0.f);
        uint2 o; o.x = packbf(r0, r1); o.y = packbf(r2, r3);
        *(uint2*)(out + ((size_t)node << 6) + 2 * f) = o;
    }
}

// ---------- agg2: quarter-wave uint2 lanes -> 4 rows per gather instruction ----------
__global__ __launch_bounds__(256) void agg2_k(const unsigned* __restrict__ h,
                                              const int* __restrict__ row_ptr,
                                              const int* __restrict__ cnt,
                                              const int* __restrict__ colv,
                                              const float* __restrict__ dinv,
                                              const float* __restrict__ bias,
                                              float* __restrict__ out, int Nn, int E) {
    int node = blockIdx.x * 4 + (threadIdx.x >> 6);
    if (node >= Nn) return;
    int lane = threadIdx.x & 63;
    int p = lane >> 4;   // quarter: which edge of a group of 4
    int f = lane & 15;   // feats 4f..4f+3 (uint2 of row of 32 uints)
    float di = dinv[node];
    int start = row_ptr[node];
    int deg = cnt[node];

    float a0, a1, a2, a3;
    {
        uint2 hv = *(const uint2*)(h + ((size_t)node << 5) + 2 * f);
        float2 xa = bfpair(hv.x), xb = bfpair(hv.y);
        float w0 = (p == 0) ? di * di : 0.f;
        a0 = w0 * xa.x; a1 = w0 * xa.y; a2 = w0 * xb.x; a3 = w0 * xb.y;
    }
    for (int base = 0; base < deg; base += 64) {
        int idx = base + lane;
        int ci = start + idx; if (ci >= E) ci = E - 1;
        int sl = colv[ci];
        float wl = (idx < deg) ? dinv[sl] : 0.f;
        int m = deg - base; if (m > 64) m = 64;
        int j = 0;
        for (; j + 16 <= m; j += 16) {   // 16 edges = 4 quad loads in flight
            int q0 = j + p, q1 = j + 4 + p, q2 = j + 8 + p, q3 = j + 12 + p;
            int s0 = __shfl(sl, q0), s1 = __shfl(sl, q1);
            int s2 = __shfl(sl, q2), s3 = __shfl(sl, q3);
            float e0 = di * __shfl(wl, q0), e1 = di * __shfl(wl, q1);
            float e2 = di * __shfl(wl, q2), e3 = di * __shfl(wl, q3);
            uint2 u0 = *(const uint2*)(h + ((size_t)s0 << 5) + 2 * f);
            uint2 u1 = *(const uint2*)(h + ((size_t)s1 << 5) + 2 * f);
            uint2 u2 = *(const uint2*)(h + ((size_t)s2 << 5) + 2 * f);
            uint2 u3 = *(const uint2*)(h + ((size_t)s3 << 5) + 2 * f);
            { float2 xa = bfpair(u0.x), xb = bfpair(u0.y);
              a0 = fmaf(e0, xa.x, a0); a1 = fmaf(e0, xa.y, a1);
              a2 = fmaf(e0, xb.x, a2); a3 = fmaf(e0, xb.y, a3); }
            { float2 xa = bfpair(u1.x), xb = bfpair(u1.y);
              a0 = fmaf(e1, xa.x, a0); a1 = fmaf(e1, xa.y, a1);
              a2 = fmaf(e1, xb.x, a2); a3 = fmaf(e1, xb.y, a3); }
            { float2 xa = bfpair(u2.x), xb = bfpair(u2.y);
              a0 = fmaf(e2, xa.x, a0); a1 = fmaf(e2, xa.y, a1);
              a2 = fmaf(e2, xb.x, a2); a3 = fmaf(e2, xb.y, a3); }
            { float2 xa = bfpair(u3.x), xb = bfpair(u3.y);
              a0 = fmaf(e3, xa.x, a0); a1 = fmaf(e3, xa.y, a1);
              a2 = fmaf(e3, xb.x, a2); a3 = fmaf(e3, xb.y, a3); }
        }
        for (; j < m; j += 4) {   // q = j+p <= 63 (j <= 60 here since m <= 64)
            int q = j + p;
            int s = __shfl(sl, q);
            float e = di * __shfl(wl, q);
            uint2 u = *(const uint2*)(h + ((size_t)s << 5) + 2 * f);
            float2 xa = bfpair(u.x), xb = bfpair(u.y);
            a0 = fmaf(e, xa.x, a0); a1 = fmaf(e, xa.y, a1);
            a2 = fmaf(e, xb.x, a2); a3 = fmaf(e, xb.y, a3);
        }
    }
    a0 += __shfl_xor(a0, 16, 64); a1 += __shfl_xor(a1, 16, 64);
    a2 += __shfl_xor(a2, 16, 64); a3 += __shfl_xor(a3, 16, 64);
    a0 += __shfl_xor(a0, 32, 64); a1 += __shfl_xor(a1, 32, 64);
    a2 += __shfl_xor(a2, 32, 64); a3 += __shfl_xor(a3, 32, 64);
    if (p == 0) {
        float4 bv = *(const float4*)(bias + 4 * f);
        float4 r = make_float4(a0 + bv.x, a1 + bv.y, a2 + bv.z, a3 + bv.w);
        *(float4*)&out[((size_t)node << 6) + 4 * f] = r;
    }
}

// ---------- launch ----------
extern "C" void kernel_launch(void* const* d_in, const int* in_sizes, int n_in,
                              void* d_out, int out_size, void* d_ws, size_t ws_size,
                              hipStream_t stream) {
    const float* x  = (const float*)d_in[0];
    const void*  ei = d_in[1];
    const float* W1 = (const float*)d_in[2];
    const float* b1 = (const float*)d_in[3];
    const float* W2 = (const float*)d_in[4];
    const float* b2 = (const float*)d_in[5];

    const int N = N_NODES;
    const int E = in_sizes[1] / 2;
    const int NB = NBLK * NBUCK;

    char* w = (char*)d_ws;
    size_t off = 0;
    auto take = [&](size_t bytes) {
        void* p = w + off;
        off = (off + bytes + 255) & ~(size_t)255;
        return p;
    };
    int*   flag    = (int*)take(2 * sizeof(int));
    int*   tot     = flag + 1;
    int*   cnt     = (int*)take((size_t)N * 4);
    int*   row_ptr = (int*)take((size_t)N * 4);
    int*   bsumA   = (int*)take(256 * 4);
    int*   bsumB   = (int*)take(256 * 4);
    int*   bhist   = (int*)take((size_t)NB * 4);
    int*   bbase   = (int*)take((size_t)NB * 4);
    float* dinv    = (float*)take((size_t)N * 4);
    unsigned* pairs = (unsigned*)take((size_t)E * 4);
    int*   colv    = (int*)take((size_t)E * 4);
    unsigned short* w1bf = (unsigned short*)take(128 * 128 * 2);
    unsigned short* w2bf = (unsigned short*)take(64 * 128 * 2);
    unsigned* hr   = (unsigned*)take((size_t)N * 64 * 4);
    unsigned* h2   = (unsigned*)take((size_t)N * 32 * 4);
    (void)ws_size; (void)n_in; (void)out_size;

    unsigned* h1 = (unsigned*)d_out;

    const int nscanN = (N + 1023) / 1024;
    const int nscanB = (NB + 1023) / 1024;

    detect64_k<<<1, 64, 0, stream>>>((const unsigned long long*)ei, flag);
    count1_k<<<NBLK, 256, 0, stream>>>(ei, flag, bhist, E);
    scan1_k<<<nscanB, 256, 0, stream>>>(bhist, bbase, bsumB, NB);
    scan2_k<<<1, 256, 0, stream>>>(bsumB, nscanB);
    scanadd_k<<<nscanB, 256, 0, stream>>>(bsumB, bbase, bhist, tot, NB);
    write1_k<<<NBLK, 256, 0, stream>>>(ei, flag, bbase, pairs, E);
    degree_k<<<NBUCK, 256, 0, stream>>>(pairs, bbase, tot, cnt, N);
    scan1_k<<<nscanN, 256, 0, stream>>>(cnt, row_ptr, bsumA, N);
    scan2_k<<<1, 256, 0, stream>>>(bsumA, nscanN);
    scan3_k<<<nscanN, 256, 0, stream>>>(bsumA, cnt, row_ptr, dinv, N);
    fill3_k<<<NBUCK, 256, 0, stream>>>(pairs, bbase, tot, row_ptr, colv, N);
    prep_w_k<<<64, 256, 0, stream>>>(W1, W2, w1bf, w2bf);

    gemm1_k<<<(N + 63) / 64, 256, 0, stream>>>(x, w1bf, h1, N);
    agg1_k<<<(N + 3) / 4, 256, 0, stream>>>(h1, row_ptr, cnt, colv, dinv, b1, hr, N, E);
    gemm2_k<<<(N + 63) / 64, 256, 0, stream>>>(hr, w2bf, h2, N);
    agg2_k<<<(N + 3) / 4, 256, 0, stream>>>(h2, row_ptr, cnt, colv, dinv, b2, (float*)d_out, N, E);
}